// Round 8
// baseline (288.033 us; speedup 1.0000x reference)
//
#include <hip/hip_runtime.h>
#include <math.h>

#define N_NODES 50000
#define N_EDGES 800000
#define D 128
#define N_LAYERS 3

#define FCHUNK 1024                              // edges per fill chunk (4/thread)
#define NCHUNK ((N_EDGES + FCHUNK - 1) / FCHUNK) // 782 fill blocks
#define GROUPS 8                                 // counter-split groups
#define GSLOT 16                                 // csr slots per (node, group)
#define ROWSLOT (GROUPS * GSLOT)                 // 128 slots per node row
#define PREPB ((N_LAYERS * D * D) / 256)         // 192 blocks for W transpose
#define CNT8B ((N_NODES * GROUPS + 255) / 256)   // 1563 blocks for cnt8 zero
#define LINB ((N_NODES + 63) / 64)               // 782 linear blocks

typedef _Float16 half8 __attribute__((ext_vector_type(8)));
typedef _Float16 half4 __attribute__((ext_vector_type(4)));
typedef float f32x4 __attribute__((ext_vector_type(4)));

// ---------------------------------------------------------------------------
// Prep: W transpose to f16 [l][n][k] + zero the 8-way split degree counters.
// ---------------------------------------------------------------------------
__global__ __launch_bounds__(256) void prep_kernel(
    const float* __restrict__ W, _Float16* __restrict__ Wt, int* __restrict__ cnt8)
{
    if (blockIdx.x < PREPB) {
        int idx = blockIdx.x * 256 + threadIdx.x;
        int l = idx >> 14, rem = idx & (D * D - 1);
        int k = rem >> 7, n = rem & 127;
        Wt[l * D * D + n * D + k] = (_Float16)W[idx];
    } else {
        int i = (blockIdx.x - PREPB) * 256 + threadIdx.x;
        if (i < N_NODES * GROUPS) cnt8[i] = 0;
    }
}

// ---------------------------------------------------------------------------
// MFMA linear + fused sr:  hout = leaky_relu(A @ W + b);  sr[n] = hout[n].awr
// Block = 4 waves x 16 rows. W^T staged in TWO 64-col halves (16.6 KB LDS ->
// 6 blocks/CU).
// FUSEFILL (layer 0): blocks >= LINB run the CSR fill, R8 restructure:
//  - single scan (no 8x rescan+filter): block fi handles chunk fi's 1024
//    edges, 1 int4-pair per thread, 4 independent atomics in flight.
//  - 8-way SPLIT counters cnt8[s*8+g] (g = fi&7): same-address atomic chain
//    depth drops 16 -> ~2 (tests the chain-serialization theory).
//  - u32 csr stores (native dword, no sub-dword RMW merge at TCC), value
//    pre-shifted dst<<8 so gather's LDS entry needs no shift.
//  - group g owns slots [g*16, g*16+16) of the node's 128-slot row ->
//    deterministic positions, no cross-group coordination.
// [R2/R5/R6 measured: fill ~45-50us regardless of occupancy (35->62%),
//  standalone vs fused, ILP width -> NOT SIMD-side-bound.]
// ---------------------------------------------------------------------------
template <bool F32IN, bool FUSEFILL>
__global__ __launch_bounds__(256, 6) void linear_mfma_kernel(
    const void* __restrict__ Ain, const _Float16* __restrict__ Wt,
    const float* __restrict__ b, const float* __restrict__ awr,
    _Float16* __restrict__ hout, float* __restrict__ sr,
    const int* __restrict__ esrc, const int* __restrict__ edst,
    int* __restrict__ cnt8, int* __restrict__ csr32)
{
    __shared__ _Float16 Wl[64 * 130];  // 16,640 B

    if (FUSEFILL && blockIdx.x >= LINB) {
        int fi = blockIdx.x - LINB;
        int g = fi & 7;
        int base = fi * FCHUNK;
        int ecnt = N_EDGES - base;
        if (ecnt > FCHUNK) ecnt = FCHUNK;
        int i = threadIdx.x * 4;
        if (i < ecnt) {
            int4 s4 = *(const int4*)(esrc + base + i);
            int4 d4 = *(const int4*)(edst + base + i);
            int pos;
            pos = atomicAdd(cnt8 + s4.x * GROUPS + g, 1);
            if (pos < GSLOT) csr32[(size_t)s4.x * ROWSLOT + g * GSLOT + pos] = d4.x << 8;
            pos = atomicAdd(cnt8 + s4.y * GROUPS + g, 1);
            if (pos < GSLOT) csr32[(size_t)s4.y * ROWSLOT + g * GSLOT + pos] = d4.y << 8;
            pos = atomicAdd(cnt8 + s4.z * GROUPS + g, 1);
            if (pos < GSLOT) csr32[(size_t)s4.z * ROWSLOT + g * GSLOT + pos] = d4.z << 8;
            pos = atomicAdd(cnt8 + s4.w * GROUPS + g, 1);
            if (pos < GSLOT) csr32[(size_t)s4.w * ROWSLOT + g * GSLOT + pos] = d4.w << 8;
        }
        return;
    }

    int tid = threadIdx.x;
    int wid = tid >> 6, lane = tid & 63;
    int m = lane & 15, q = lane >> 4;
    int rowbase = blockIdx.x * 64 + wid * 16;
    int row = rowbase + m;

    half8 a[4];
    if (row < N_NODES) {
        if (F32IN) {
            const float* ar = (const float*)Ain + (size_t)row * D;
#pragma unroll
            for (int s = 0; s < 4; ++s) {
                float4 lo = *(const float4*)(ar + s * 32 + q * 8);
                float4 hi = *(const float4*)(ar + s * 32 + q * 8 + 4);
                a[s][0] = (_Float16)lo.x; a[s][1] = (_Float16)lo.y;
                a[s][2] = (_Float16)lo.z; a[s][3] = (_Float16)lo.w;
                a[s][4] = (_Float16)hi.x; a[s][5] = (_Float16)hi.y;
                a[s][6] = (_Float16)hi.z; a[s][7] = (_Float16)hi.w;
            }
        } else {
            const _Float16* ar = (const _Float16*)Ain + (size_t)row * D;
#pragma unroll
            for (int s = 0; s < 4; ++s)
                a[s] = *(const half8*)(ar + s * 32 + q * 8);
        }
    } else {
#pragma unroll
        for (int s = 0; s < 4; ++s)
#pragma unroll
            for (int j = 0; j < 8; ++j) a[s][j] = (_Float16)0.f;
    }

    f32x4 acc[8];
#pragma unroll
    for (int t = 0; t < 8; ++t) acc[t] = (f32x4)(0.f);

#pragma unroll
    for (int hh = 0; hh < 2; ++hh) {
        for (int j = tid * 8; j < 64 * D; j += 2048) {
            int n = j >> 7, k = j & 127;
            *(half8*)(&Wl[n * 130 + k]) = *(const half8*)(Wt + (hh * 64 + n) * D + k);
        }
        __syncthreads();
#pragma unroll
        for (int s = 0; s < 4; ++s) {
#pragma unroll
            for (int t = 0; t < 4; ++t) {
                half8 bf = *(const half8*)(&Wl[(t * 16 + m) * 130 + s * 32 + q * 8]);
                acc[hh * 4 + t] = __builtin_amdgcn_mfma_f32_16x16x32_f16(a[s], bf, acc[hh * 4 + t], 0, 0, 0);
            }
        }
        __syncthreads();
    }

    float sp[4] = {0.f, 0.f, 0.f, 0.f};
#pragma unroll
    for (int t = 0; t < 8; ++t) {
        int col = t * 16 + m;
        float bc = b[col];
        float ac = awr[col];
#pragma unroll
        for (int r = 0; r < 4; ++r) {
            int orow = rowbase + q * 4 + r;
            float v = acc[t][r] + bc;
            v = v > 0.f ? v : 0.2f * v;
            sp[r] = fmaf(v, ac, sp[r]);
            if (orow < N_NODES)
                hout[(size_t)orow * D + col] = (_Float16)v;
        }
    }
#pragma unroll
    for (int r = 0; r < 4; ++r) {
#pragma unroll
        for (int o = 1; o < 16; o <<= 1)
            sp[r] += __shfl_xor(sp[r], o, 64);
    }
    if (m == 0) {
#pragma unroll
        for (int r = 0; r < 4; ++r) {
            int orow = rowbase + q * 4 + r;
            if (orow < N_NODES) sr[orow] = sp[r];
        }
    }
}

// ---------------------------------------------------------------------------
// Fused softmax + gather, one wave per node. Grouped-CSR densify preamble:
// 8 per-group counts -> 8-lane exclusive shfl-scan -> each valid (g,j) slot
// gets dense rank pg+j into prow. Downstream (16B half8 loads, 4 rows/instr,
// 16 rows in flight) identical to R7's verified loop.
// ---------------------------------------------------------------------------
__global__ __launch_bounds__(256, 8) void gather_kernel(
    const int* __restrict__ cnt8, const int* __restrict__ csr32,
    const float* __restrict__ sr, const _Float16* __restrict__ h,
    _Float16* __restrict__ out16, float* __restrict__ out32)
{
    __shared__ int plds[4][2 * ROWSLOT + 8];
    int wid = threadIdx.x >> 6, lane = threadIdx.x & 63;
    int r = lane >> 4, c = lane & 15;
    int n = blockIdx.x * 4 + wid;
    int* prow = plds[wid];

    // --- counts + exclusive prefix over the 8 groups (8-lane shfl scan) ---
    int myc = cnt8[n * GROUPS + (lane & 7)];
    myc = myc > GSLOT ? GSLOT : myc;
    int p = myc;
#pragma unroll
    for (int o = 1; o < 8; o <<= 1) {
        int u = __shfl_up(p, o, 8);
        if ((lane & 7) >= o) p += u;
    }
    int excl = p - myc;                 // exclusive prefix of group (lane&7)
    int deg = __shfl(p, 7, 8);          // total stored edges for node n
    int gl = lane >> 3;                 // the group this lane covers
    int cg = __shfl(myc, gl, 8);        // count of group gl
    int pg = __shfl(excl, gl, 8);       // rank base of group gl
    const int* ce = csr32 + (size_t)n * ROWSLOT + gl * GSLOT;

    // --- softmax: round t covers slot j = (lane&7) + t*8 of group gl ---
    float ev[2];
    float m = -INFINITY;
#pragma unroll
    for (int t = 0; t < 2; ++t) {
        int j = (lane & 7) + t * 8;
        if (j < cg) {
            int dofs = ce[j];           // dst<<8 (byte offset of h row)
            prow[2 * (pg + j)] = dofs;
            float e = sr[dofs >> 8];
            ev[t] = e;
            m = fmaxf(m, e);
        }
    }
    for (int o = 32; o > 0; o >>= 1) m = fmaxf(m, __shfl_xor(m, o, 64));

    float s = 0.f;
#pragma unroll
    for (int t = 0; t < 2; ++t) {
        int j = (lane & 7) + t * 8;
        if (j < cg) {
            float a = __expf(ev[t] - m);
            prow[2 * (pg + j) + 1] = __float_as_int(a);
            s += a;
        }
    }
    for (int o = 32; o > 0; o >>= 1) s += __shfl_xor(s, o, 64);
    float inv = (deg > 0) ? 1.f / s : 0.f;

    // --- weighted gather: 16B/lane, 4 rows per instr, 16 rows in flight ---
    float acc[8];
#pragma unroll
    for (int j = 0; j < 8; ++j) acc[j] = 0.f;
    const char* hb = (const char*)h + c * 16;

    int k = 0;
    int degU = deg & ~15;
    for (; k < degU; k += 16) {
        int2 p0 = *(const int2*)(prow + 2 * (k + r));
        int2 p1 = *(const int2*)(prow + 2 * (k + 4 + r));
        int2 p2 = *(const int2*)(prow + 2 * (k + 8 + r));
        int2 p3 = *(const int2*)(prow + 2 * (k + 12 + r));
        half8 h0 = *(const half8*)(hb + p0.x);
        half8 h1 = *(const half8*)(hb + p1.x);
        half8 h2 = *(const half8*)(hb + p2.x);
        half8 h3 = *(const half8*)(hb + p3.x);
        float a0 = __int_as_float(p0.y);
        float a1 = __int_as_float(p1.y);
        float a2 = __int_as_float(p2.y);
        float a3 = __int_as_float(p3.y);
#pragma unroll
        for (int j = 0; j < 8; ++j) acc[j] = fmaf((float)h0[j], a0, acc[j]);
#pragma unroll
        for (int j = 0; j < 8; ++j) acc[j] = fmaf((float)h1[j], a1, acc[j]);
#pragma unroll
        for (int j = 0; j < 8; ++j) acc[j] = fmaf((float)h2[j], a2, acc[j]);
#pragma unroll
        for (int j = 0; j < 8; ++j) acc[j] = fmaf((float)h3[j], a3, acc[j]);
    }
    for (; k < deg; k += 4) {
        int kk = k + r;
        int2 pp = (kk < deg) ? *(const int2*)(prow + 2 * kk) : make_int2(0, 0);
        half8 hv = *(const half8*)(hb + pp.x);
        float a = __int_as_float(pp.y);
#pragma unroll
        for (int j = 0; j < 8; ++j) acc[j] = fmaf((float)hv[j], a, acc[j]);
    }

    // reduce across the 4 row-groups (lane stride 16)
#pragma unroll
    for (int j = 0; j < 8; ++j) {
        acc[j] += __shfl_xor(acc[j], 16, 64);
        acc[j] += __shfl_xor(acc[j], 32, 64);
    }

    if (r == 0) {  // lanes 0..15 hold the full row, 8 dims each
        float rv[8];
#pragma unroll
        for (int j = 0; j < 8; ++j) rv[j] = fmaxf(acc[j] * inv, 0.f);
        if (out16) {
            half8 o;
#pragma unroll
            for (int j = 0; j < 8; ++j) o[j] = (_Float16)rv[j];
            *(half8*)(out16 + (size_t)n * D + c * 8) = o;
        } else {
            float4 lo = make_float4(rv[0], rv[1], rv[2], rv[3]);
            float4 hi = make_float4(rv[4], rv[5], rv[6], rv[7]);
            *(float4*)(out32 + (size_t)n * D + c * 8) = lo;
            *(float4*)(out32 + (size_t)n * D + c * 8 + 4) = hi;
        }
    }
}

extern "C" void kernel_launch(void* const* d_in, const int* in_sizes, int n_in,
                              void* d_out, int out_size, void* d_ws, size_t ws_size,
                              hipStream_t stream)
{
    const float* x      = (const float*)d_in[0];
    const int*   esrc   = (const int*)d_in[1];
    const int*   edst   = (const int*)d_in[2];
    const float* lin_w  = (const float*)d_in[3];
    const float* lin_b  = (const float*)d_in[4];
    const float* attn_w = (const float*)d_in[5];
    float* out = (float*)d_out;

    char* ws = (char*)d_ws;
    _Float16* h16A  = (_Float16*)(ws);                // 12,800,000 B
    _Float16* h16B  = (_Float16*)(ws + 12800000);     // 12,800,000 B
    float*    sr    = (float*)(ws + 25600000);        // 200,000 B
    int*      cnt8  = (int*)(ws + 25800000);          // 1,600,000 B
    int*      csr32 = (int*)(ws + 27400000);          // 25,600,000 B
    _Float16* Wt16  = (_Float16*)(ws + 53000000);     // 98,304 B

    // Prep: W transpose + cnt8 zero.
    prep_kernel<<<PREPB + CNT8B, 256, 0, stream>>>(lin_w, Wt16, cnt8);

    for (int l = 0; l < N_LAYERS; ++l) {
        bool last = (l == N_LAYERS - 1);
        if (l == 0)
            linear_mfma_kernel<true, true><<<LINB + NCHUNK, 256, 0, stream>>>(
                x, Wt16, lin_b, attn_w + D, h16A, sr,
                esrc, edst, cnt8, csr32);
        else
            linear_mfma_kernel<false, false><<<LINB, 256, 0, stream>>>(
                h16B, Wt16 + (size_t)l * D * D, lin_b + (size_t)l * D,
                attn_w + (size_t)l * 2 * D + D, h16A, sr,
                nullptr, nullptr, nullptr, nullptr);
        gather_kernel<<<N_NODES / 4, 256, 0, stream>>>(
            cnt8, csr32, sr, h16A,
            last ? (_Float16*)nullptr : h16B, last ? out : nullptr);
    }
}